// Round 7
// baseline (680.375 us; speedup 1.0000x reference)
//
#include <hip/hip_runtime.h>
#include <hip/hip_bf16.h>

// SNN forward: conv1(3->64,3x3,p1) -> IF -> pool2 -> conv2(64->64) -> IF -> pool2
//              -> fc1(16384->4096) -> IF -> fc2(4096->10) -> IF -> mean over T
// T=8 N=32 IMG=64.
// conv2 and fc1 use bf16 MFMA: spikes are exactly 0/1 (exact in bf16); fp32
// weights are 3-way bf16 split (hi+mid+lo, residual <= 2^-25|w|) -> three MFMAs
// into one fp32 accumulator == fp32 dot product to within fp32 rounding noise.
// fc1 (R7): R6 showed three ~2000cyc/it pipes (MFMA 1860, VALU-split 2000,
// LDS ~1700 from A+W staging with 2-4x read duplication) serializing to 6000.
// A (spk2, L2-resident: each 1MB ks-slice read by 64 nt-blocks) now loads
// DIRECTLY global->register, double-buffered one K-step ahead (static avA/avB
// naming, 2-unrolled loop). LDS keeps only the W slab (triple-buffer DMA,
// counted vmcnt: end-of-it vmcnt(5) = W(it+2)+A(it+1)x4 outstanding).
// conv2 (R5): A tile (zero-padded, 42.5 KB) DMA-staged per t; inner loop is
// pure ds_read_b128 + MFMA, no bounds checks; 16B-slot swizzle on DMA source.

#define T_STEPS 8
#define NB      32
#define CMID    64

typedef __bf16 bf16x2 __attribute__((ext_vector_type(2)));
typedef __bf16 bf16x4 __attribute__((ext_vector_type(4)));
typedef __bf16 bf16x8 __attribute__((ext_vector_type(8)));
typedef short  s16x8  __attribute__((ext_vector_type(8)));
typedef float  f32x4  __attribute__((ext_vector_type(4)));

struct Split3 { float h, m, l; };
__device__ __forceinline__ Split3 split3(float x) {
    Split3 s;
    __bf16 h = (__bf16)x;
    float r1 = x - (float)h;
    __bf16 m = (__bf16)r1;
    float r2 = r1 - (float)m;
    __bf16 l = (__bf16)r2;
    s.h = (float)h; s.m = (float)m; s.l = (float)l;
    return s;
}

// split 8 fp32 (two float4) into three bf16 MFMA fragments (hi/mid/lo)
__device__ __forceinline__ void split3v8(float4 a, float4 b,
                                         s16x8& fh, s16x8& fm, s16x8& fl) {
    float x[8] = {a.x, a.y, a.z, a.w, b.x, b.y, b.z, b.w};
    s16x8 h, m, l;
#pragma unroll
    for (int j = 0; j < 8; j++) {
        __bf16 ch = (__bf16)x[j];
        float r1 = x[j] - (float)ch;
        __bf16 cm = (__bf16)r1;
        float r2 = r1 - (float)cm;
        __bf16 cl = (__bf16)r2;
        h[j] = __builtin_bit_cast(short, ch);
        m[j] = __builtin_bit_cast(short, cm);
        l[j] = __builtin_bit_cast(short, cl);
    }
    fh = h; fm = m; fl = l;
}

// async global(16B/lane) -> LDS, wave-uniform dest base + lane*16
__device__ __forceinline__ void load_lds16(const void* g, void* l) {
    __builtin_amdgcn_global_load_lds(
        (const __attribute__((address_space(1))) void*)g,
        (__attribute__((address_space(3))) void*)l, 16, 0, 0);
}

// ------------------------------------------------- w2 -> 3-way-split frag order
// w2[co][ci][ky][kx] fp32 -> w2s[ch][tap][kh][oh][sp][lane][j] bf16 where
// co = ch*32+oh*16+(lane&15), ci = kh*32+(lane>>4)*8+j, tap = ky*3+kx.
// This is exactly the MFMA B-fragment order; conv2 blocks memcpy it into LDS.
__global__ void k_w2s(const float* __restrict__ w2, __bf16* __restrict__ w2s) {
    int idx = blockIdx.x * 256 + threadIdx.x;   // 36864 total
    int j    = idx & 7;
    int lane = (idx >> 3) & 63;
    int oh   = (idx >> 9) & 1;
    int kh   = (idx >> 10) & 1;
    int g    = idx >> 11;          // ch*9 + tap, 0..17
    int tap  = g % 9;
    int ch   = g / 9;
    int co = ch * 32 + oh * 16 + (lane & 15);
    int ci = kh * 32 + (lane >> 4) * 8 + j;
    float w = w2[co * 576 + ci * 9 + tap];
    Split3 s = split3(w);
    __bf16* o = w2s + (((size_t)(g * 2 + kh) * 2 + oh) * 3) * 512 + lane * 8 + j;
    o[0]    = (__bf16)s.h;
    o[512]  = (__bf16)s.m;
    o[1024] = (__bf16)s.l;
}

// ------------------------------------------ conv1 + IF + maxpool -> NHWC bf16
// Writes spk1p[tn][h][w][ci] bf16 (ci contiguous -> conv2 A-fragments are
// single 16B loads).
__global__ __launch_bounds__(256) void k_conv1_if_pool(
        const float* __restrict__ x, const float* __restrict__ w1,
        __bf16* __restrict__ spk1p) {
    int b   = blockIdx.x;               // 1024 = 32n * 8cog * 4pht
    int n   = b >> 5;
    int cog = (b >> 2) & 7;
    int pht = b & 3;
    int tid = threadIdx.x;
    int pw  = tid & 31;
    int ph  = pht * 8 + (tid >> 5);
    int ih0 = 2 * ph - 1, iw0 = 2 * pw - 1;

    float v[8][4];
#pragma unroll
    for (int a = 0; a < 8; a++)
#pragma unroll
        for (int p = 0; p < 4; p++) v[a][p] = 0.f;

    for (int t = 0; t < T_STEPS; t++) {
        const float* xb = x + (size_t)(t * NB + n) * 3 * 4096;
        float patch[3][4][4];
#pragma unroll
        for (int ci = 0; ci < 3; ci++)
#pragma unroll
            for (int dy = 0; dy < 4; dy++) {
                int ih = ih0 + dy;
                bool rok = ((unsigned)ih < 64u);
#pragma unroll
                for (int dx = 0; dx < 4; dx++) {
                    int iw = iw0 + dx;
                    patch[ci][dy][dx] = (rok && ((unsigned)iw < 64u))
                                            ? xb[ci * 4096 + ih * 64 + iw] : 0.f;
                }
            }
        bf16x8 sv;
#pragma unroll
        for (int c8 = 0; c8 < 8; c8++) {
            int co = cog * 8 + c8;
            const float* wc = w1 + co * 27;   // wave-uniform -> s_load
            float a0 = 0.f, a1 = 0.f, a2 = 0.f, a3 = 0.f;
#pragma unroll
            for (int ci = 0; ci < 3; ci++)
#pragma unroll
                for (int ky = 0; ky < 3; ky++)
#pragma unroll
                    for (int kx = 0; kx < 3; kx++) {
                        float w = wc[ci * 9 + ky * 3 + kx];
                        a0 += w * patch[ci][ky][kx];
                        a1 += w * patch[ci][ky][kx + 1];
                        a2 += w * patch[ci][ky + 1][kx];
                        a3 += w * patch[ci][ky + 1][kx + 1];
                    }
            float s0, s1, s2, s3;
            v[c8][0] += a0; s0 = (v[c8][0] >= 1.f) ? 1.f : 0.f; if (s0 > 0.f) v[c8][0] = 0.f;
            v[c8][1] += a1; s1 = (v[c8][1] >= 1.f) ? 1.f : 0.f; if (s1 > 0.f) v[c8][1] = 0.f;
            v[c8][2] += a2; s2 = (v[c8][2] >= 1.f) ? 1.f : 0.f; if (s2 > 0.f) v[c8][2] = 0.f;
            v[c8][3] += a3; s3 = (v[c8][3] >= 1.f) ? 1.f : 0.f; if (s3 > 0.f) v[c8][3] = 0.f;
            sv[c8] = (__bf16)fmaxf(fmaxf(s0, s1), fmaxf(s2, s3));
        }
        *(bf16x8*)(spk1p + ((size_t)(t * NB + n) * 1024 + ph * 32 + pw) * 64
                         + cog * 8) = sv;
    }
}

// -------------------------------- conv2 (MFMA) + IF + maxpool fused, t in-kernel
// 8 waves (mh 0..3 x oh 0..1) covering 2 strips; grid 256 = 1 block/CU.
// A tile [10 rows][34 w (zero-padded)][8 slots of 16B] DMA-staged per t;
// slot swizzle: phys = logical ^ (widx&7), inverse applied on DMA source.
__global__ __launch_bounds__(512, 2) void k_conv2_if_pool(
        const short* __restrict__ spk1p,   // [256][32][32][64] bf16 bits
        const short* __restrict__ w2s,     // [2][55296] bf16 bits (frag order)
        __bf16* __restrict__ spk2) {       // [256][64][16][16]
    int b     = blockIdx.x;                // 256 = 32n * 4s2 * 2ch
    int ch    = b & 1;
    int s2    = (b >> 1) & 3;
    int n     = b >> 3;
    int tid   = threadIdx.x;
    int lane  = tid & 63;
    int wv    = tid >> 6;                  // 0..7
    int mh    = wv >> 1, oh = wv & 1;      // mh 0..3
    int lm    = lane & 15, kq = lane >> 4;

    __shared__ short Bs[55296];            // 108 KB: 9tap x 2kh x 2oh x 3sp x 512
    __shared__ short As[10 * 34 * 64];     // 42.5 KB: [r][widx][8 slots x 8 shorts]

    {
        const uint4* src = (const uint4*)(w2s + (size_t)ch * 55296);
        uint4* dst = (uint4*)Bs;
        for (int i = tid; i < 6912; i += 512) dst[i] = src[i];
        // zero whole A tile once: pad cols (widx 0,33) + out-of-image rows
        // stay zero forever (DMA never writes them).
        uint4* za = (uint4*)As;
        for (int i = tid; i < 2720; i += 512) za[i] = (uint4){0, 0, 0, 0};
    }
    __syncthreads();
    const short* Bsw = Bs + oh * 1536;

    int wl  = lane >> 3;
    int sph = lane & 7;

    f32x4 v[4];
#pragma unroll
    for (int i = 0; i < 4; i++) v[i] = (f32x4){0.f, 0.f, 0.f, 0.f};

    int co = ch * 32 + oh * 16 + lm;
    int pH = s2 * 4 + mh;

#pragma unroll 1
    for (int t = 0; t < T_STEPS; t++) {
        const short* img = spk1p + (size_t)(t * NB + n) * 65536;

        if (t > 0) __syncthreads();        // all reads of As[t-1] done
#pragma unroll
        for (int q = 0; q < 5; q++) {
            int u = q * 8 + wv;            // 0..39, wave-uniform
            int r = u >> 2;
            int quarter = u & 3;
            int hh = s2 * 8 - 1 + r;
            if ((unsigned)hh < 32u) {
                int widx = quarter * 8 + 1 + wl;
                int slog = sph ^ (widx & 7);
                const short* src = img + (size_t)(hh * 32 + widx - 1) * 64
                                       + slog * 8;
                short* dst = As + (r * 34 + quarter * 8 + 1) * 64;
                load_lds16(src, dst);
            }
        }
        __syncthreads();                   // drains DMA (vmcnt 0): As[t] ready

        f32x4 acc[4];
#pragma unroll
        for (int i = 0; i < 4; i++) acc[i] = (f32x4){0.f, 0.f, 0.f, 0.f};

#pragma unroll 1
        for (int dy = 0; dy < 3; dy++) {
#pragma unroll 1
            for (int dx = 0; dx < 3; dx++) {
                const short* bp = Bsw + (dy * 3 + dx) * 6144 + lane * 8;
                s16x8 bf[2][3];
#pragma unroll
                for (int kh = 0; kh < 2; kh++)
#pragma unroll
                    for (int sp = 0; sp < 3; sp++)
                        bf[kh][sp] = *(const s16x8*)(bp + kh * 3072 + sp * 512);
#pragma unroll
                for (int i = 0; i < 4; i++) {
                    int r    = 2 * mh + (i >> 1) + dy;              // 0..9
                    int widx = (i & 1) * 16 + lm + dx;              // 0..33
                    const short* ap = As + (r * 34 + widx) * 64;
                    s16x8 a0 = *(const s16x8*)(ap + ((kq    ) ^ (widx & 7)) * 8);
                    s16x8 a1 = *(const s16x8*)(ap + ((kq + 4) ^ (widx & 7)) * 8);
#pragma unroll
                    for (int sp = 0; sp < 3; sp++) {
                        acc[i] = __builtin_amdgcn_mfma_f32_16x16x32_bf16(
                            a0, bf[0][sp], acc[i], 0, 0, 0);
                        acc[i] = __builtin_amdgcn_mfma_f32_16x16x32_bf16(
                            a1, bf[1][sp], acc[i], 0, 0, 0);
                    }
                }
            }
        }
        // IF (charge, fire, hard reset) then 2x2 max-pool, all within-lane
        float s[4][4];
#pragma unroll
        for (int i = 0; i < 4; i++)
#pragma unroll
            for (int r = 0; r < 4; r++) {
                float vv = v[i][r] + acc[i][r];
                float sp = (vv >= 1.f) ? 1.f : 0.f;
                s[i][r] = sp;
                v[i][r] = (sp > 0.f) ? 0.f : vv;
            }
        __bf16* op = spk2 + ((size_t)(t * NB + n) * 64 + co) * 256 + pH * 16
                   + kq * 2;
#pragma unroll
        for (int i2 = 0; i2 < 2; i2++) {
            float p0 = fmaxf(fmaxf(s[i2][0], s[i2][1]),
                             fmaxf(s[i2 + 2][0], s[i2 + 2][1]));
            float p1 = fmaxf(fmaxf(s[i2][2], s[i2][3]),
                             fmaxf(s[i2 + 2][2], s[i2 + 2][3]));
            bf16x2 pv = {(__bf16)p0, (__bf16)p1};
            *(bf16x2*)(op + i2 * 8) = pv;
        }
    }
}

// ----------------------------------------------------------- fc1 via bf16 MFMA
// 512-thread blocks (8 waves: mq 0..3 x oh 0..1), 2 blocks/CU -> 4 waves/SIMD.
// W: DMA triple-buffered LDS slab (8 KB/step), counted-vmcnt pipeline.
// A: DIRECT global->register (L2-resident, each ks-slice read by 64 blocks),
// double-buffered one K-step ahead with static avA/avB naming (2-unrolled
// loop; no runtime-indexed register arrays). End-of-it sync:
//   s_waitcnt vmcnt(5)   // W(it+2) + A(it+1)x4 may stay in flight
//   s_barrier + sched_barrier(0)
// sched_barrier(0) after the W DMA issue pins issue order so the counts hold.
// Values, MFMA order, and stores identical to R6 -> bit-identical output.
__global__ __launch_bounds__(512, 4) void k_fc1_mfma(
        const short* __restrict__ A,      // spk2 bf16 bits [256][16384]
        const float* __restrict__ W,      // fc1 [4096][16384]
        float* __restrict__ part) {       // [8][256][4096]
    int b  = blockIdx.x;                  // 512 = 64nt * 8ks
    int nt = b & 63;
    int ks = b >> 6;
    int o0 = nt * 64;
    int kbase = ks * 2048;

    int tid  = threadIdx.x;
    int lane = tid & 63;
    int wv   = tid >> 6;                  // 0..7
    int mq   = wv >> 1;                   // M quarter (64 rows)
    int oh   = wv & 1;                    // output half (32 of 64)
    int lm   = lane & 15;
    int kq   = lane >> 4;

    __shared__ float Wsm[3][2048];        // 3 x 8 KB W slab (swizzled)

    // W DMA source (inverse swizzle on source; dest is linear).
    int wrow = tid >> 3;
    int wu   = (tid & 7) ^ (wrow & 7);
    const float* gW = W + (size_t)(o0 + wrow) * 16384 + kbase + wu * 4;

    // A fragment base: row = mq*64 + i*16 + lm, k = kbase + it*32 + kq*8
    const short* gAf = A + (size_t)(mq * 64 + lm) * 16384 + kbase + kq * 8;

    // swizzled W read offsets (floats)
    int woff[2][2];
#pragma unroll
    for (int oi = 0; oi < 2; oi++) {
        int row = (2 * oh + oi) * 16 + lm;
#pragma unroll
        for (int h = 0; h < 2; h++) {
            int u = kq * 2 + h;
            woff[oi][h] = (row * 8 + (u ^ (row & 7))) * 4;
        }
    }

    f32x4 acc[4][2];
#pragma unroll
    for (int i = 0; i < 4; i++)
#pragma unroll
        for (int oi = 0; oi < 2; oi++) acc[i][oi] = (f32x4){0.f, 0.f, 0.f, 0.f};

    s16x8 avA[4], avB[4];

    // prologue: W slabs for it=0,1; A fragments for it=0
    load_lds16(gW,      &Wsm[0][wv * 256]);
    load_lds16(gW + 32, &Wsm[1][wv * 256]);
    __builtin_amdgcn_sched_barrier(0);    // pin: DMA issued before A loads
#pragma unroll
    for (int i = 0; i < 4; i++)
        avA[i] = *(const s16x8*)(gAf + (size_t)i * 16 * 16384);
    asm volatile("s_waitcnt vmcnt(5)" ::: "memory");  // W0 done (W1+A0x4 out)
    __builtin_amdgcn_s_barrier();
    __builtin_amdgcn_sched_barrier(0);

    auto body = [&](int it, s16x8* avc, s16x8* avn) {
        // 1) issue W DMA for it+2 (stays in flight across the barrier)
        if (it < 62)
            load_lds16(gW + (it + 2) * 32, &Wsm[(it + 2) % 3][wv * 256]);
        __builtin_amdgcn_sched_barrier(0);    // keep DMA oldest in vm queue
        // 2) issue A loads for it+1 (consumed next body; window = full body)
        if (it < 63) {
            const short* ga = gAf + (it + 1) * 32;
#pragma unroll
            for (int i = 0; i < 4; i++)
                avn[i] = *(const s16x8*)(ga + (size_t)i * 16 * 16384);
        }
        // 3) W raw fp32 from LDS, 3-way split in registers
        const float* ws = Wsm[it % 3];
        float4 wraw[2][2];
#pragma unroll
        for (int oi = 0; oi < 2; oi++)
#pragma unroll
            for (int h = 0; h < 2; h++)
                wraw[oi][h] = *(const float4*)(ws + woff[oi][h]);
        s16x8 bfr[3][2];                  // [sp][oi]
#pragma unroll
        for (int oi = 0; oi < 2; oi++)
            split3v8(wraw[oi][0], wraw[oi][1],
                     bfr[0][oi], bfr[1][oi], bfr[2][oi]);
        // 4) MFMA cluster
        __builtin_amdgcn_s_setprio(1);
#pragma unroll
        for (int i = 0; i < 4; i++)
#pragma unroll
            for (int oi = 0; oi < 2; oi++) {
                acc[i][oi] = __builtin_amdgcn_mfma_f32_16x16x32_bf16(
                    avc[i], bfr[0][oi], acc[i][oi], 0, 0, 0);
                acc[i][oi] = __builtin_amdgcn_mfma_f32_16x16x32_bf16(
                    avc[i], bfr[1][oi], acc[i][oi], 0, 0, 0);
                acc[i][oi] = __builtin_amdgcn_mfma_f32_16x16x32_bf16(
                    avc[i], bfr[2][oi], acc[i][oi], 0, 0, 0);
            }
        __builtin_amdgcn_s_setprio(0);
        // 5) counted sync: W(it+1) complete; W(it+2)+A(it+1) stay in flight
        if (it < 62) {
            asm volatile("s_waitcnt vmcnt(5)" ::: "memory");
            __builtin_amdgcn_s_barrier();
            __builtin_amdgcn_sched_barrier(0);
        } else if (it == 62) {
            asm volatile("s_waitcnt vmcnt(4)" ::: "memory");
            __builtin_amdgcn_s_barrier();
            __builtin_amdgcn_sched_barrier(0);
        }
    };

#pragma unroll 1
    for (int j = 0; j < 32; ++j) {
        body(2 * j,     avA, avB);
        body(2 * j + 1, avB, avA);
    }

    int col = lane & 15;
    int rq  = (lane >> 4) * 4;
#pragma unroll
    for (int i = 0; i < 4; i++)
#pragma unroll
        for (int oi = 0; oi < 2; oi++)
#pragma unroll
            for (int r = 0; r < 4; r++) {
                int m = mq * 64 + i * 16 + rq + r;
                int o = o0 + (2 * oh + oi) * 16 + col;
                part[((size_t)ks * 256 + m) * 4096 + o] = acc[i][oi][r];
            }
}

// ----------------------------------------------- K-split reduce + IF for fc1
__global__ void k_fc1_if(const float* __restrict__ part,
                         float* __restrict__ spk3) {
    int idx = blockIdx.x * 256 + threadIdx.x;   // 131072
    int o = idx & 4095;
    int n = idx >> 12;
    float v = 0.f;
    for (int t = 0; t < T_STEPS; t++) {
        int m = t * NB + n;
        float s = 0.f;
#pragma unroll
        for (int ks = 0; ks < 8; ks++)
            s += part[((size_t)ks * 256 + m) * 4096 + o];
        v += s;
        float sp = (v >= 1.f) ? 1.f : 0.f;
        if (sp > 0.f) v = 0.f;
        spk3[(size_t)m * 4096 + o] = sp;
    }
}

// ------------------------------------------------------ fc2 + IF + time-mean
__global__ __launch_bounds__(256) void k_fc2_if_mean(
        const float* __restrict__ spk3, const float* __restrict__ fc2,
        float* __restrict__ out) {
    int b = blockIdx.x;                  // 320 = 32n * 10o
    int n = b / 10, o = b % 10;
    const float* wr = fc2 + o * 4096;
    __shared__ float red[256];
    int tid = threadIdx.x;
    float v = 0.f, cnt = 0.f;
    for (int t = 0; t < T_STEPS; t++) {
        const float* row = spk3 + (size_t)(t * NB + n) * 4096;
        float p = 0.f;
        for (int i = tid; i < 4096; i += 256) p += row[i] * wr[i];
        red[tid] = p;
        __syncthreads();
        for (int s = 128; s > 0; s >>= 1) {
            if (tid < s) red[tid] += red[tid + s];
            __syncthreads();
        }
        if (tid == 0) {
            v += red[0];
            float sp = (v >= 1.f) ? 1.f : 0.f;
            cnt += sp;
            if (sp > 0.f) v = 0.f;
        }
        __syncthreads();
    }
    if (tid == 0) out[n * 10 + o] = cnt * 0.125f;
}

// ---------------------------------------------------------------------- launch
extern "C" void kernel_launch(void* const* d_in, const int* in_sizes, int n_in,
                              void* d_out, int out_size, void* d_ws, size_t ws_size,
                              hipStream_t stream) {
    const float* x   = (const float*)d_in[0];   // [8,32,3,64,64]
    const float* w1  = (const float*)d_in[1];   // [64,3,3,3]
    const float* w2  = (const float*)d_in[2];   // [64,64,3,3]
    const float* fc1 = (const float*)d_in[3];   // [4096,16384]
    const float* fc2 = (const float*)d_in[4];   // [10,4096]
    float* out = (float*)d_out;                 // [32,10]

    float* ws = (float*)d_ws;
    // workspace layout (float slots)
    const size_t off_w2s   = 0;                          // 57344 (110592 bf16)
    const size_t off_spk1p = 57344;                      // 8388608 (16.8M bf16)
    const size_t off_spk2  = off_spk1p + 8388608;        // 2097152 (4.2M bf16)
    const size_t off_part  = off_spk2 + 2097152;         // 8388608
    const size_t off_spk3  = off_part + 8388608;         // 1048576
    __bf16* w2s   = (__bf16*)(ws + off_w2s);
    __bf16* spk1p = (__bf16*)(ws + off_spk1p);
    __bf16* spk2  = (__bf16*)(ws + off_spk2);
    float*  part  = ws + off_part;
    float*  spk3  = ws + off_spk3;

    k_w2s<<<144, 256, 0, stream>>>(w2, w2s);
    k_conv1_if_pool<<<1024, 256, 0, stream>>>(x, w1, spk1p);
    k_conv2_if_pool<<<256, 512, 0, stream>>>((const short*)spk1p,
                                             (const short*)w2s, spk2);
    k_fc1_mfma<<<512, 512, 0, stream>>>((const short*)spk2, fc1, part);
    k_fc1_if<<<512, 256, 0, stream>>>(part, spk3);
    k_fc2_if_mean<<<320, 256, 0, stream>>>(spk3, fc2, out);
}

// Round 8
// 673.829 us; speedup vs baseline: 1.0097x; 1.0097x over previous
//
#include <hip/hip_runtime.h>
#include <hip/hip_bf16.h>

// SNN forward: conv1(3->64,3x3,p1) -> IF -> pool2 -> conv2(64->64) -> IF -> pool2
//              -> fc1(16384->4096) -> IF -> fc2(4096->10) -> IF -> mean over T
// T=8 N=32 IMG=64.
// conv2 and fc1 use bf16 MFMA: spikes are exactly 0/1 (exact in bf16); fp32
// weights are 3-way bf16 split (hi+mid+lo, residual <= 2^-25|w|) -> three MFMAs
// into one fp32 accumulator == fp32 dot product to within fp32 rounding noise.
// fc1 (R8): R7's A-direct regressed (16 rows x 32KB stride alias one L1 set ->
// L1 thrash; DMA slabs are contiguous and immune) -> reverted to R5 structure
// (A+W DMA double-buffer, __syncthreads). R5-R7 all plateau ~155-160us with NO
// pipe >33% busy at 2 blocks/CU: barrier-convoy latency-bound. Lever = TLP:
// K-split 8->16 (grid 1024), LDS 48KB -> 3 blocks/CU, launch_bounds(512,6)
// -> 24 waves/CU. Other blocks' waves fill each block's barrier gaps.
// conv2 (R5): A tile (zero-padded, 42.5 KB) DMA-staged per t; inner loop is
// pure ds_read_b128 + MFMA, no bounds checks; 16B-slot swizzle on DMA source.

#define T_STEPS 8
#define NB      32
#define CMID    64

typedef __bf16 bf16x2 __attribute__((ext_vector_type(2)));
typedef __bf16 bf16x4 __attribute__((ext_vector_type(4)));
typedef __bf16 bf16x8 __attribute__((ext_vector_type(8)));
typedef short  s16x8  __attribute__((ext_vector_type(8)));
typedef float  f32x4  __attribute__((ext_vector_type(4)));

struct Split3 { float h, m, l; };
__device__ __forceinline__ Split3 split3(float x) {
    Split3 s;
    __bf16 h = (__bf16)x;
    float r1 = x - (float)h;
    __bf16 m = (__bf16)r1;
    float r2 = r1 - (float)m;
    __bf16 l = (__bf16)r2;
    s.h = (float)h; s.m = (float)m; s.l = (float)l;
    return s;
}

// split 8 fp32 (two float4) into three bf16 MFMA fragments (hi/mid/lo)
__device__ __forceinline__ void split3v8(float4 a, float4 b,
                                         s16x8& fh, s16x8& fm, s16x8& fl) {
    float x[8] = {a.x, a.y, a.z, a.w, b.x, b.y, b.z, b.w};
    s16x8 h, m, l;
#pragma unroll
    for (int j = 0; j < 8; j++) {
        __bf16 ch = (__bf16)x[j];
        float r1 = x[j] - (float)ch;
        __bf16 cm = (__bf16)r1;
        float r2 = r1 - (float)cm;
        __bf16 cl = (__bf16)r2;
        h[j] = __builtin_bit_cast(short, ch);
        m[j] = __builtin_bit_cast(short, cm);
        l[j] = __builtin_bit_cast(short, cl);
    }
    fh = h; fm = m; fl = l;
}

// async global(16B/lane) -> LDS, wave-uniform dest base + lane*16
__device__ __forceinline__ void load_lds16(const void* g, void* l) {
    __builtin_amdgcn_global_load_lds(
        (const __attribute__((address_space(1))) void*)g,
        (__attribute__((address_space(3))) void*)l, 16, 0, 0);
}

// ------------------------------------------------- w2 -> 3-way-split frag order
// w2[co][ci][ky][kx] fp32 -> w2s[ch][tap][kh][oh][sp][lane][j] bf16 where
// co = ch*32+oh*16+(lane&15), ci = kh*32+(lane>>4)*8+j, tap = ky*3+kx.
// This is exactly the MFMA B-fragment order; conv2 blocks memcpy it into LDS.
__global__ void k_w2s(const float* __restrict__ w2, __bf16* __restrict__ w2s) {
    int idx = blockIdx.x * 256 + threadIdx.x;   // 36864 total
    int j    = idx & 7;
    int lane = (idx >> 3) & 63;
    int oh   = (idx >> 9) & 1;
    int kh   = (idx >> 10) & 1;
    int g    = idx >> 11;          // ch*9 + tap, 0..17
    int tap  = g % 9;
    int ch   = g / 9;
    int co = ch * 32 + oh * 16 + (lane & 15);
    int ci = kh * 32 + (lane >> 4) * 8 + j;
    float w = w2[co * 576 + ci * 9 + tap];
    Split3 s = split3(w);
    __bf16* o = w2s + (((size_t)(g * 2 + kh) * 2 + oh) * 3) * 512 + lane * 8 + j;
    o[0]    = (__bf16)s.h;
    o[512]  = (__bf16)s.m;
    o[1024] = (__bf16)s.l;
}

// ------------------------------------------ conv1 + IF + maxpool -> NHWC bf16
// Writes spk1p[tn][h][w][ci] bf16 (ci contiguous -> conv2 A-fragments are
// single 16B loads).
__global__ __launch_bounds__(256) void k_conv1_if_pool(
        const float* __restrict__ x, const float* __restrict__ w1,
        __bf16* __restrict__ spk1p) {
    int b   = blockIdx.x;               // 1024 = 32n * 8cog * 4pht
    int n   = b >> 5;
    int cog = (b >> 2) & 7;
    int pht = b & 3;
    int tid = threadIdx.x;
    int pw  = tid & 31;
    int ph  = pht * 8 + (tid >> 5);
    int ih0 = 2 * ph - 1, iw0 = 2 * pw - 1;

    float v[8][4];
#pragma unroll
    for (int a = 0; a < 8; a++)
#pragma unroll
        for (int p = 0; p < 4; p++) v[a][p] = 0.f;

    for (int t = 0; t < T_STEPS; t++) {
        const float* xb = x + (size_t)(t * NB + n) * 3 * 4096;
        float patch[3][4][4];
#pragma unroll
        for (int ci = 0; ci < 3; ci++)
#pragma unroll
            for (int dy = 0; dy < 4; dy++) {
                int ih = ih0 + dy;
                bool rok = ((unsigned)ih < 64u);
#pragma unroll
                for (int dx = 0; dx < 4; dx++) {
                    int iw = iw0 + dx;
                    patch[ci][dy][dx] = (rok && ((unsigned)iw < 64u))
                                            ? xb[ci * 4096 + ih * 64 + iw] : 0.f;
                }
            }
        bf16x8 sv;
#pragma unroll
        for (int c8 = 0; c8 < 8; c8++) {
            int co = cog * 8 + c8;
            const float* wc = w1 + co * 27;   // wave-uniform -> s_load
            float a0 = 0.f, a1 = 0.f, a2 = 0.f, a3 = 0.f;
#pragma unroll
            for (int ci = 0; ci < 3; ci++)
#pragma unroll
                for (int ky = 0; ky < 3; ky++)
#pragma unroll
                    for (int kx = 0; kx < 3; kx++) {
                        float w = wc[ci * 9 + ky * 3 + kx];
                        a0 += w * patch[ci][ky][kx];
                        a1 += w * patch[ci][ky][kx + 1];
                        a2 += w * patch[ci][ky + 1][kx];
                        a3 += w * patch[ci][ky + 1][kx + 1];
                    }
            float s0, s1, s2, s3;
            v[c8][0] += a0; s0 = (v[c8][0] >= 1.f) ? 1.f : 0.f; if (s0 > 0.f) v[c8][0] = 0.f;
            v[c8][1] += a1; s1 = (v[c8][1] >= 1.f) ? 1.f : 0.f; if (s1 > 0.f) v[c8][1] = 0.f;
            v[c8][2] += a2; s2 = (v[c8][2] >= 1.f) ? 1.f : 0.f; if (s2 > 0.f) v[c8][2] = 0.f;
            v[c8][3] += a3; s3 = (v[c8][3] >= 1.f) ? 1.f : 0.f; if (s3 > 0.f) v[c8][3] = 0.f;
            sv[c8] = (__bf16)fmaxf(fmaxf(s0, s1), fmaxf(s2, s3));
        }
        *(bf16x8*)(spk1p + ((size_t)(t * NB + n) * 1024 + ph * 32 + pw) * 64
                         + cog * 8) = sv;
    }
}

// -------------------------------- conv2 (MFMA) + IF + maxpool fused, t in-kernel
// 8 waves (mh 0..3 x oh 0..1) covering 2 strips; grid 256 = 1 block/CU.
// A tile [10 rows][34 w (zero-padded)][8 slots of 16B] DMA-staged per t;
// slot swizzle: phys = logical ^ (widx&7), inverse applied on DMA source.
__global__ __launch_bounds__(512, 2) void k_conv2_if_pool(
        const short* __restrict__ spk1p,   // [256][32][32][64] bf16 bits
        const short* __restrict__ w2s,     // [2][55296] bf16 bits (frag order)
        __bf16* __restrict__ spk2) {       // [256][64][16][16]
    int b     = blockIdx.x;                // 256 = 32n * 4s2 * 2ch
    int ch    = b & 1;
    int s2    = (b >> 1) & 3;
    int n     = b >> 3;
    int tid   = threadIdx.x;
    int lane  = tid & 63;
    int wv    = tid >> 6;                  // 0..7
    int mh    = wv >> 1, oh = wv & 1;      // mh 0..3
    int lm    = lane & 15, kq = lane >> 4;

    __shared__ short Bs[55296];            // 108 KB: 9tap x 2kh x 2oh x 3sp x 512
    __shared__ short As[10 * 34 * 64];     // 42.5 KB: [r][widx][8 slots x 8 shorts]

    {
        const uint4* src = (const uint4*)(w2s + (size_t)ch * 55296);
        uint4* dst = (uint4*)Bs;
        for (int i = tid; i < 6912; i += 512) dst[i] = src[i];
        // zero whole A tile once: pad cols (widx 0,33) + out-of-image rows
        // stay zero forever (DMA never writes them).
        uint4* za = (uint4*)As;
        for (int i = tid; i < 2720; i += 512) za[i] = (uint4){0, 0, 0, 0};
    }
    __syncthreads();
    const short* Bsw = Bs + oh * 1536;

    int wl  = lane >> 3;
    int sph = lane & 7;

    f32x4 v[4];
#pragma unroll
    for (int i = 0; i < 4; i++) v[i] = (f32x4){0.f, 0.f, 0.f, 0.f};

    int co = ch * 32 + oh * 16 + lm;
    int pH = s2 * 4 + mh;

#pragma unroll 1
    for (int t = 0; t < T_STEPS; t++) {
        const short* img = spk1p + (size_t)(t * NB + n) * 65536;

        if (t > 0) __syncthreads();        // all reads of As[t-1] done
#pragma unroll
        for (int q = 0; q < 5; q++) {
            int u = q * 8 + wv;            // 0..39, wave-uniform
            int r = u >> 2;
            int quarter = u & 3;
            int hh = s2 * 8 - 1 + r;
            if ((unsigned)hh < 32u) {
                int widx = quarter * 8 + 1 + wl;
                int slog = sph ^ (widx & 7);
                const short* src = img + (size_t)(hh * 32 + widx - 1) * 64
                                       + slog * 8;
                short* dst = As + (r * 34 + quarter * 8 + 1) * 64;
                load_lds16(src, dst);
            }
        }
        __syncthreads();                   // drains DMA (vmcnt 0): As[t] ready

        f32x4 acc[4];
#pragma unroll
        for (int i = 0; i < 4; i++) acc[i] = (f32x4){0.f, 0.f, 0.f, 0.f};

#pragma unroll 1
        for (int dy = 0; dy < 3; dy++) {
#pragma unroll 1
            for (int dx = 0; dx < 3; dx++) {
                const short* bp = Bsw + (dy * 3 + dx) * 6144 + lane * 8;
                s16x8 bf[2][3];
#pragma unroll
                for (int kh = 0; kh < 2; kh++)
#pragma unroll
                    for (int sp = 0; sp < 3; sp++)
                        bf[kh][sp] = *(const s16x8*)(bp + kh * 3072 + sp * 512);
#pragma unroll
                for (int i = 0; i < 4; i++) {
                    int r    = 2 * mh + (i >> 1) + dy;              // 0..9
                    int widx = (i & 1) * 16 + lm + dx;              // 0..33
                    const short* ap = As + (r * 34 + widx) * 64;
                    s16x8 a0 = *(const s16x8*)(ap + ((kq    ) ^ (widx & 7)) * 8);
                    s16x8 a1 = *(const s16x8*)(ap + ((kq + 4) ^ (widx & 7)) * 8);
#pragma unroll
                    for (int sp = 0; sp < 3; sp++) {
                        acc[i] = __builtin_amdgcn_mfma_f32_16x16x32_bf16(
                            a0, bf[0][sp], acc[i], 0, 0, 0);
                        acc[i] = __builtin_amdgcn_mfma_f32_16x16x32_bf16(
                            a1, bf[1][sp], acc[i], 0, 0, 0);
                    }
                }
            }
        }
        // IF (charge, fire, hard reset) then 2x2 max-pool, all within-lane
        float s[4][4];
#pragma unroll
        for (int i = 0; i < 4; i++)
#pragma unroll
            for (int r = 0; r < 4; r++) {
                float vv = v[i][r] + acc[i][r];
                float sp = (vv >= 1.f) ? 1.f : 0.f;
                s[i][r] = sp;
                v[i][r] = (sp > 0.f) ? 0.f : vv;
            }
        __bf16* op = spk2 + ((size_t)(t * NB + n) * 64 + co) * 256 + pH * 16
                   + kq * 2;
#pragma unroll
        for (int i2 = 0; i2 < 2; i2++) {
            float p0 = fmaxf(fmaxf(s[i2][0], s[i2][1]),
                             fmaxf(s[i2 + 2][0], s[i2 + 2][1]));
            float p1 = fmaxf(fmaxf(s[i2][2], s[i2][3]),
                             fmaxf(s[i2 + 2][2], s[i2 + 2][3]));
            bf16x2 pv = {(__bf16)p0, (__bf16)p1};
            *(bf16x2*)(op + i2 * 8) = pv;
        }
    }
}

// ----------------------------------------------------------- fc1 via bf16 MFMA
// R5 structure (proven best): per K-step(32) DMA-stage A slab (256 rows x 32k
// bf16 = 16 KB, 2 issues) and W slab (64 rows x 32k fp32 = 8 KB, 1 issue) into
// double-buffered LDS (48 KB); __syncthreads at iteration end drains DMA ->
// full-iteration latency window, zero VGPR cost.
// R8: K-split 16 (grid 1024 = 64nt x 16ks, 32 its of 1024 k) -> 3 blocks/CU
// (LDS 48KB fits 3), launch_bounds(512,6) -> 24 waves/CU. TLP fills the
// barrier-convoy gaps that capped R5-R7 at ~2 blocks/CU / 42% occupancy.
// Swizzles (2-way = free):
//   W: 16B-unit-in-row u ^= (row&7)   A: 16B-slot-in-row s ^= ((r>>1)&3)
// applied on the DMA SOURCE address (DMA writes LDS linearly) and on ds_reads.
__global__ __launch_bounds__(512, 6) void k_fc1_mfma(
        const short* __restrict__ A,      // spk2 bf16 bits [256][16384]
        const float* __restrict__ W,      // fc1 [4096][16384]
        float* __restrict__ part) {       // [16][256][4096]
    int b  = blockIdx.x;                  // 1024 = 64nt * 16ks
    int nt = b & 63;
    int ks = b >> 6;
    int o0 = nt * 64;
    int kbase = ks * 1024;

    int tid  = threadIdx.x;
    int lane = tid & 63;
    int wv   = tid >> 6;                  // 0..7
    int mq   = wv >> 1;                   // M quarter (64 rows)
    int oh   = wv & 1;                    // output half (32 of 64)
    int lm   = lane & 15;
    int kq   = lane >> 4;

    __shared__ short Asm[2][8192];        // 2 x 16 KB A slab (swizzled)
    __shared__ float Wsm[2][2048];        // 2 x 8 KB  W slab (swizzled)

    // DMA source addresses (inverse swizzle on source; dest is linear).
    // W: phys unit p = tid (0..511): row=p>>3, u=(p&7)^(row&7)
    int wrow = tid >> 3;
    int wu   = (tid & 7) ^ (wrow & 7);
    const float* gW = W + (size_t)(o0 + wrow) * 16384 + kbase + wu * 4;
    // A: phys unit p = q*512+tid: r=p>>2, slot=(p&3)^((r>>1)&3)
    const short* gA[2];
#pragma unroll
    for (int q = 0; q < 2; q++) {
        int p = q * 512 + tid;
        int r = p >> 2;
        int c = (p & 3) ^ ((r >> 1) & 3);
        gA[q] = A + (size_t)r * 16384 + kbase + c * 8;
    }

    // LDS read offsets (swizzled)
    int aoff[4];                          // shorts
#pragma unroll
    for (int i = 0; i < 4; i++) {
        int r = mq * 64 + i * 16 + lm;
        aoff[i] = (r * 4 + (kq ^ ((r >> 1) & 3))) * 8;
    }
    int woff[2][2];                       // floats
#pragma unroll
    for (int oi = 0; oi < 2; oi++) {
        int row = (2 * oh + oi) * 16 + lm;
#pragma unroll
        for (int h = 0; h < 2; h++) {
            int u = kq * 2 + h;
            woff[oi][h] = (row * 8 + (u ^ (row & 7))) * 4;
        }
    }

    f32x4 acc[4][2];
#pragma unroll
    for (int i = 0; i < 4; i++)
#pragma unroll
        for (int oi = 0; oi < 2; oi++) acc[i][oi] = (f32x4){0.f, 0.f, 0.f, 0.f};

    // prologue: DMA it=0 slabs into buf 0
    load_lds16(gW, &Wsm[0][wv * 256]);
    load_lds16(gA[0], &Asm[0][wv * 512]);
    load_lds16(gA[1], &Asm[0][4096 + wv * 512]);
    __syncthreads();

#pragma unroll 1
    for (int it = 0; it < 32; ++it) {
        int bf = it & 1;
        // async prefetch next slabs (no VGPR cost; drained at loop-end barrier)
        if (it < 31) {
            load_lds16(gW + (it + 1) * 32, &Wsm[bf ^ 1][wv * 256]);
            load_lds16(gA[0] + (it + 1) * 32, &Asm[bf ^ 1][wv * 512]);
            load_lds16(gA[1] + (it + 1) * 32, &Asm[bf ^ 1][4096 + wv * 512]);
        }

        const short* as = Asm[bf];
        const float* ws = Wsm[bf];

        s16x8 av[4];
#pragma unroll
        for (int i = 0; i < 4; i++)
            av[i] = *(const s16x8*)(as + aoff[i]);

        float4 wraw[2][2];
#pragma unroll
        for (int oi = 0; oi < 2; oi++)
#pragma unroll
            for (int h = 0; h < 2; h++)
                wraw[oi][h] = *(const float4*)(ws + woff[oi][h]);

        s16x8 bfr[3][2];                  // [sp][oi]
#pragma unroll
        for (int oi = 0; oi < 2; oi++)
            split3v8(wraw[oi][0], wraw[oi][1],
                     bfr[0][oi], bfr[1][oi], bfr[2][oi]);

#pragma unroll
        for (int i = 0; i < 4; i++)
#pragma unroll
            for (int oi = 0; oi < 2; oi++) {
                acc[i][oi] = __builtin_amdgcn_mfma_f32_16x16x32_bf16(
                    av[i], bfr[0][oi], acc[i][oi], 0, 0, 0);
                acc[i][oi] = __builtin_amdgcn_mfma_f32_16x16x32_bf16(
                    av[i], bfr[1][oi], acc[i][oi], 0, 0, 0);
                acc[i][oi] = __builtin_amdgcn_mfma_f32_16x16x32_bf16(
                    av[i], bfr[2][oi], acc[i][oi], 0, 0, 0);
            }

        __syncthreads();                  // drains DMA (vmcnt 0) + swaps
    }

    int col = lane & 15;
    int rq  = (lane >> 4) * 4;
#pragma unroll
    for (int i = 0; i < 4; i++)
#pragma unroll
        for (int oi = 0; oi < 2; oi++)
#pragma unroll
            for (int r = 0; r < 4; r++) {
                int m = mq * 64 + i * 16 + rq + r;
                int o = o0 + (2 * oh + oi) * 16 + col;
                part[((size_t)ks * 256 + m) * 4096 + o] = acc[i][oi][r];
            }
}

// ----------------------------------------------- K-split reduce + IF for fc1
__global__ void k_fc1_if(const float* __restrict__ part,
                         float* __restrict__ spk3) {
    int idx = blockIdx.x * 256 + threadIdx.x;   // 131072
    int o = idx & 4095;
    int n = idx >> 12;
    float v = 0.f;
    for (int t = 0; t < T_STEPS; t++) {
        int m = t * NB + n;
        float s = 0.f;
#pragma unroll
        for (int ks = 0; ks < 16; ks++)
            s += part[((size_t)ks * 256 + m) * 4096 + o];
        v += s;
        float sp = (v >= 1.f) ? 1.f : 0.f;
        if (sp > 0.f) v = 0.f;
        spk3[(size_t)m * 4096 + o] = sp;
    }
}

// ------------------------------------------------------ fc2 + IF + time-mean
__global__ __launch_bounds__(256) void k_fc2_if_mean(
        const float* __restrict__ spk3, const float* __restrict__ fc2,
        float* __restrict__ out) {
    int b = blockIdx.x;                  // 320 = 32n * 10o
    int n = b / 10, o = b % 10;
    const float* wr = fc2 + o * 4096;
    __shared__ float red[256];
    int tid = threadIdx.x;
    float v = 0.f, cnt = 0.f;
    for (int t = 0; t < T_STEPS; t++) {
        const float* row = spk3 + (size_t)(t * NB + n) * 4096;
        float p = 0.f;
        for (int i = tid; i < 4096; i += 256) p += row[i] * wr[i];
        red[tid] = p;
        __syncthreads();
        for (int s = 128; s > 0; s >>= 1) {
            if (tid < s) red[tid] += red[tid + s];
            __syncthreads();
        }
        if (tid == 0) {
            v += red[0];
            float sp = (v >= 1.f) ? 1.f : 0.f;
            cnt += sp;
            if (sp > 0.f) v = 0.f;
        }
        __syncthreads();
    }
    if (tid == 0) out[n * 10 + o] = cnt * 0.125f;
}

// ---------------------------------------------------------------------- launch
extern "C" void kernel_launch(void* const* d_in, const int* in_sizes, int n_in,
                              void* d_out, int out_size, void* d_ws, size_t ws_size,
                              hipStream_t stream) {
    const float* x   = (const float*)d_in[0];   // [8,32,3,64,64]
    const float* w1  = (const float*)d_in[1];   // [64,3,3,3]
    const float* w2  = (const float*)d_in[2];   // [64,64,3,3]
    const float* fc1 = (const float*)d_in[3];   // [4096,16384]
    const float* fc2 = (const float*)d_in[4];   // [10,4096]
    float* out = (float*)d_out;                 // [32,10]

    float* ws = (float*)d_ws;
    // workspace layout (float slots)
    const size_t off_w2s   = 0;                          // 57344 (110592 bf16)
    const size_t off_spk1p = 57344;                      // 8388608 (16.8M bf16)
    const size_t off_spk2  = off_spk1p + 8388608;        // 2097152 (4.2M bf16)
    const size_t off_part  = off_spk2 + 2097152;         // 16777216 ([16][256][4096])
    const size_t off_spk3  = off_part + 16777216;        // 1048576
    __bf16* w2s   = (__bf16*)(ws + off_w2s);
    __bf16* spk1p = (__bf16*)(ws + off_spk1p);
    __bf16* spk2  = (__bf16*)(ws + off_spk2);
    float*  part  = ws + off_part;
    float*  spk3  = ws + off_spk3;

    k_w2s<<<144, 256, 0, stream>>>(w2, w2s);
    k_conv1_if_pool<<<1024, 256, 0, stream>>>(x, w1, spk1p);
    k_conv2_if_pool<<<256, 512, 0, stream>>>((const short*)spk1p,
                                             (const short*)w2s, spk2);
    k_fc1_mfma<<<1024, 512, 0, stream>>>((const short*)spk2, fc1, part);
    k_fc1_if<<<512, 256, 0, stream>>>(part, spk3);
    k_fc2_if_mean<<<320, 256, 0, stream>>>(spk3, fc2, out);
}

// Round 9
// 628.859 us; speedup vs baseline: 1.0819x; 1.0715x over previous
//
#include <hip/hip_runtime.h>
#include <hip/hip_bf16.h>

// SNN forward: conv1(3->64,3x3,p1) -> IF -> pool2 -> conv2(64->64) -> IF -> pool2
//              -> fc1(16384->4096) -> IF -> fc2(4096->10) -> IF -> mean over T
// T=8 N=32 IMG=64.
// conv2 and fc1 use bf16 MFMA: spikes are exactly 0/1 (exact in bf16); fp32
// weights are 3-way bf16 split (hi+mid+lo, residual <= 2^-25|w|) -> three MFMAs
// into one fp32 accumulator == fp32 dot product to within fp32 rounding noise.
// fc1 (R9): R5-R8 counters stable at MFMA ~23% / VALU ~30% -- root cause: all
// 4 mq-waves split3 the IDENTICAL W fragments (woff is mq-independent) = 4x
// duplicated VALU competing with MFMA issue. Now the 512 threads split the W
// slab cooperatively ONCE per K-step (1 float4/thread global->reg, split3 x4,
// 3x ds_write_b64 into a pre-split bf16 buffer); MFMA waves read ready bf16
// fragments. W-fp32 LDS staging gone; A keeps DMA double-buffer (proven).
// Same split3 bit values + same MFMA order -> bit-identical output.
// conv2 (R5): A tile (zero-padded, 42.5 KB) DMA-staged per t; inner loop is
// pure ds_read_b128 + MFMA, no bounds checks; 16B-slot swizzle on DMA source.

#define T_STEPS 8
#define NB      32
#define CMID    64

typedef __bf16 bf16x2 __attribute__((ext_vector_type(2)));
typedef __bf16 bf16x4 __attribute__((ext_vector_type(4)));
typedef __bf16 bf16x8 __attribute__((ext_vector_type(8)));
typedef short  s16x4  __attribute__((ext_vector_type(4)));
typedef short  s16x8  __attribute__((ext_vector_type(8)));
typedef float  f32x4  __attribute__((ext_vector_type(4)));

struct Split3 { float h, m, l; };
__device__ __forceinline__ Split3 split3(float x) {
    Split3 s;
    __bf16 h = (__bf16)x;
    float r1 = x - (float)h;
    __bf16 m = (__bf16)r1;
    float r2 = r1 - (float)m;
    __bf16 l = (__bf16)r2;
    s.h = (float)h; s.m = (float)m; s.l = (float)l;
    return s;
}

// split 4 fp32 into three bf16x4 (hi/mid/lo), bit-identical to split3()
__device__ __forceinline__ void split3w4(float4 v, s16x4& fh, s16x4& fm,
                                         s16x4& fl) {
    float x[4] = {v.x, v.y, v.z, v.w};
    s16x4 h, m, l;
#pragma unroll
    for (int j = 0; j < 4; j++) {
        __bf16 ch = (__bf16)x[j];
        float r1 = x[j] - (float)ch;
        __bf16 cm = (__bf16)r1;
        float r2 = r1 - (float)cm;
        __bf16 cl = (__bf16)r2;
        h[j] = __builtin_bit_cast(short, ch);
        m[j] = __builtin_bit_cast(short, cm);
        l[j] = __builtin_bit_cast(short, cl);
    }
    fh = h; fm = m; fl = l;
}

// async global(16B/lane) -> LDS, wave-uniform dest base + lane*16
__device__ __forceinline__ void load_lds16(const void* g, void* l) {
    __builtin_amdgcn_global_load_lds(
        (const __attribute__((address_space(1))) void*)g,
        (__attribute__((address_space(3))) void*)l, 16, 0, 0);
}

// ------------------------------------------------- w2 -> 3-way-split frag order
// w2[co][ci][ky][kx] fp32 -> w2s[ch][tap][kh][oh][sp][lane][j] bf16 where
// co = ch*32+oh*16+(lane&15), ci = kh*32+(lane>>4)*8+j, tap = ky*3+kx.
// This is exactly the MFMA B-fragment order; conv2 blocks memcpy it into LDS.
__global__ void k_w2s(const float* __restrict__ w2, __bf16* __restrict__ w2s) {
    int idx = blockIdx.x * 256 + threadIdx.x;   // 36864 total
    int j    = idx & 7;
    int lane = (idx >> 3) & 63;
    int oh   = (idx >> 9) & 1;
    int kh   = (idx >> 10) & 1;
    int g    = idx >> 11;          // ch*9 + tap, 0..17
    int tap  = g % 9;
    int ch   = g / 9;
    int co = ch * 32 + oh * 16 + (lane & 15);
    int ci = kh * 32 + (lane >> 4) * 8 + j;
    float w = w2[co * 576 + ci * 9 + tap];
    Split3 s = split3(w);
    __bf16* o = w2s + (((size_t)(g * 2 + kh) * 2 + oh) * 3) * 512 + lane * 8 + j;
    o[0]    = (__bf16)s.h;
    o[512]  = (__bf16)s.m;
    o[1024] = (__bf16)s.l;
}

// ------------------------------------------ conv1 + IF + maxpool -> NHWC bf16
// Writes spk1p[tn][h][w][ci] bf16 (ci contiguous -> conv2 A-fragments are
// single 16B loads).
__global__ __launch_bounds__(256) void k_conv1_if_pool(
        const float* __restrict__ x, const float* __restrict__ w1,
        __bf16* __restrict__ spk1p) {
    int b   = blockIdx.x;               // 1024 = 32n * 8cog * 4pht
    int n   = b >> 5;
    int cog = (b >> 2) & 7;
    int pht = b & 3;
    int tid = threadIdx.x;
    int pw  = tid & 31;
    int ph  = pht * 8 + (tid >> 5);
    int ih0 = 2 * ph - 1, iw0 = 2 * pw - 1;

    float v[8][4];
#pragma unroll
    for (int a = 0; a < 8; a++)
#pragma unroll
        for (int p = 0; p < 4; p++) v[a][p] = 0.f;

    for (int t = 0; t < T_STEPS; t++) {
        const float* xb = x + (size_t)(t * NB + n) * 3 * 4096;
        float patch[3][4][4];
#pragma unroll
        for (int ci = 0; ci < 3; ci++)
#pragma unroll
            for (int dy = 0; dy < 4; dy++) {
                int ih = ih0 + dy;
                bool rok = ((unsigned)ih < 64u);
#pragma unroll
                for (int dx = 0; dx < 4; dx++) {
                    int iw = iw0 + dx;
                    patch[ci][dy][dx] = (rok && ((unsigned)iw < 64u))
                                            ? xb[ci * 4096 + ih * 64 + iw] : 0.f;
                }
            }
        bf16x8 sv;
#pragma unroll
        for (int c8 = 0; c8 < 8; c8++) {
            int co = cog * 8 + c8;
            const float* wc = w1 + co * 27;   // wave-uniform -> s_load
            float a0 = 0.f, a1 = 0.f, a2 = 0.f, a3 = 0.f;
#pragma unroll
            for (int ci = 0; ci < 3; ci++)
#pragma unroll
                for (int ky = 0; ky < 3; ky++)
#pragma unroll
                    for (int kx = 0; kx < 3; kx++) {
                        float w = wc[ci * 9 + ky * 3 + kx];
                        a0 += w * patch[ci][ky][kx];
                        a1 += w * patch[ci][ky][kx + 1];
                        a2 += w * patch[ci][ky + 1][kx];
                        a3 += w * patch[ci][ky + 1][kx + 1];
                    }
            float s0, s1, s2, s3;
            v[c8][0] += a0; s0 = (v[c8][0] >= 1.f) ? 1.f : 0.f; if (s0 > 0.f) v[c8][0] = 0.f;
            v[c8][1] += a1; s1 = (v[c8][1] >= 1.f) ? 1.f : 0.f; if (s1 > 0.f) v[c8][1] = 0.f;
            v[c8][2] += a2; s2 = (v[c8][2] >= 1.f) ? 1.f : 0.f; if (s2 > 0.f) v[c8][2] = 0.f;
            v[c8][3] += a3; s3 = (v[c8][3] >= 1.f) ? 1.f : 0.f; if (s3 > 0.f) v[c8][3] = 0.f;
            sv[c8] = (__bf16)fmaxf(fmaxf(s0, s1), fmaxf(s2, s3));
        }
        *(bf16x8*)(spk1p + ((size_t)(t * NB + n) * 1024 + ph * 32 + pw) * 64
                         + cog * 8) = sv;
    }
}

// -------------------------------- conv2 (MFMA) + IF + maxpool fused, t in-kernel
// 8 waves (mh 0..3 x oh 0..1) covering 2 strips; grid 256 = 1 block/CU.
// A tile [10 rows][34 w (zero-padded)][8 slots of 16B] DMA-staged per t;
// slot swizzle: phys = logical ^ (widx&7), inverse applied on DMA source.
__global__ __launch_bounds__(512, 2) void k_conv2_if_pool(
        const short* __restrict__ spk1p,   // [256][32][32][64] bf16 bits
        const short* __restrict__ w2s,     // [2][55296] bf16 bits (frag order)
        __bf16* __restrict__ spk2) {       // [256][64][16][16]
    int b     = blockIdx.x;                // 256 = 32n * 4s2 * 2ch
    int ch    = b & 1;
    int s2    = (b >> 1) & 3;
    int n     = b >> 3;
    int tid   = threadIdx.x;
    int lane  = tid & 63;
    int wv    = tid >> 6;                  // 0..7
    int mh    = wv >> 1, oh = wv & 1;      // mh 0..3
    int lm    = lane & 15, kq = lane >> 4;

    __shared__ short Bs[55296];            // 108 KB: 9tap x 2kh x 2oh x 3sp x 512
    __shared__ short As[10 * 34 * 64];     // 42.5 KB: [r][widx][8 slots x 8 shorts]

    {
        const uint4* src = (const uint4*)(w2s + (size_t)ch * 55296);
        uint4* dst = (uint4*)Bs;
        for (int i = tid; i < 6912; i += 512) dst[i] = src[i];
        // zero whole A tile once: pad cols (widx 0,33) + out-of-image rows
        // stay zero forever (DMA never writes them).
        uint4* za = (uint4*)As;
        for (int i = tid; i < 2720; i += 512) za[i] = (uint4){0, 0, 0, 0};
    }
    __syncthreads();
    const short* Bsw = Bs + oh * 1536;

    int wl  = lane >> 3;
    int sph = lane & 7;

    f32x4 v[4];
#pragma unroll
    for (int i = 0; i < 4; i++) v[i] = (f32x4){0.f, 0.f, 0.f, 0.f};

    int co = ch * 32 + oh * 16 + lm;
    int pH = s2 * 4 + mh;

#pragma unroll 1
    for (int t = 0; t < T_STEPS; t++) {
        const short* img = spk1p + (size_t)(t * NB + n) * 65536;

        if (t > 0) __syncthreads();        // all reads of As[t-1] done
#pragma unroll
        for (int q = 0; q < 5; q++) {
            int u = q * 8 + wv;            // 0..39, wave-uniform
            int r = u >> 2;
            int quarter = u & 3;
            int hh = s2 * 8 - 1 + r;
            if ((unsigned)hh < 32u) {
                int widx = quarter * 8 + 1 + wl;
                int slog = sph ^ (widx & 7);
                const short* src = img + (size_t)(hh * 32 + widx - 1) * 64
                                       + slog * 8;
                short* dst = As + (r * 34 + quarter * 8 + 1) * 64;
                load_lds16(src, dst);
            }
        }
        __syncthreads();                   // drains DMA (vmcnt 0): As[t] ready

        f32x4 acc[4];
#pragma unroll
        for (int i = 0; i < 4; i++) acc[i] = (f32x4){0.f, 0.f, 0.f, 0.f};

#pragma unroll 1
        for (int dy = 0; dy < 3; dy++) {
#pragma unroll 1
            for (int dx = 0; dx < 3; dx++) {
                const short* bp = Bsw + (dy * 3 + dx) * 6144 + lane * 8;
                s16x8 bf[2][3];
#pragma unroll
                for (int kh = 0; kh < 2; kh++)
#pragma unroll
                    for (int sp = 0; sp < 3; sp++)
                        bf[kh][sp] = *(const s16x8*)(bp + kh * 3072 + sp * 512);
#pragma unroll
                for (int i = 0; i < 4; i++) {
                    int r    = 2 * mh + (i >> 1) + dy;              // 0..9
                    int widx = (i & 1) * 16 + lm + dx;              // 0..33
                    const short* ap = As + (r * 34 + widx) * 64;
                    s16x8 a0 = *(const s16x8*)(ap + ((kq    ) ^ (widx & 7)) * 8);
                    s16x8 a1 = *(const s16x8*)(ap + ((kq + 4) ^ (widx & 7)) * 8);
#pragma unroll
                    for (int sp = 0; sp < 3; sp++) {
                        acc[i] = __builtin_amdgcn_mfma_f32_16x16x32_bf16(
                            a0, bf[0][sp], acc[i], 0, 0, 0);
                        acc[i] = __builtin_amdgcn_mfma_f32_16x16x32_bf16(
                            a1, bf[1][sp], acc[i], 0, 0, 0);
                    }
                }
            }
        }
        // IF (charge, fire, hard reset) then 2x2 max-pool, all within-lane
        float s[4][4];
#pragma unroll
        for (int i = 0; i < 4; i++)
#pragma unroll
            for (int r = 0; r < 4; r++) {
                float vv = v[i][r] + acc[i][r];
                float sp = (vv >= 1.f) ? 1.f : 0.f;
                s[i][r] = sp;
                v[i][r] = (sp > 0.f) ? 0.f : vv;
            }
        __bf16* op = spk2 + ((size_t)(t * NB + n) * 64 + co) * 256 + pH * 16
                   + kq * 2;
#pragma unroll
        for (int i2 = 0; i2 < 2; i2++) {
            float p0 = fmaxf(fmaxf(s[i2][0], s[i2][1]),
                             fmaxf(s[i2 + 2][0], s[i2 + 2][1]));
            float p1 = fmaxf(fmaxf(s[i2][2], s[i2][3]),
                             fmaxf(s[i2 + 2][2], s[i2 + 2][3]));
            bf16x2 pv = {(__bf16)p0, (__bf16)p1};
            *(bf16x2*)(op + i2 * 8) = pv;
        }
    }
}

// ----------------------------------------------------------- fc1 via bf16 MFMA
// 512-thread blocks (8 waves: mq 0..3 x oh 0..1), grid 512 = 2 blocks/CU exact.
// Per K-step(32):
//   A slab (256 x 32k bf16, 16 KB) DMA double-buffered (as R5; swizzle
//     slot ^= ((r>>1)&3) applied on DMA source + reads).
//   W slab split ONCE cooperatively: each thread loads 1 float4 of W fp32
//     (row=tid>>3, k=(tid&7)*4; coalesced 128B/row segments), split3 x4,
//     writes 3x bf16x4 into Wbf[buf][sp][64 rows][32 k] with 16B-chunk swizzle
//     kc ^= ((row>>1)&3). MFMA waves read ready bf16 fragments (b128, 2-way).
//   Split for it+1 runs during it's MFMAs (disjoint buffers); W(it+2) float4
//   prefetch has a full body to land; one __syncthreads per step.
// Same split3 bits + same MFMA order as R5-R8 -> bit-identical output.
// LDS = 32 KB (A) + 24 KB (Wbf) = 56 KB -> 2 blocks/CU, 4 waves/SIMD.
__global__ __launch_bounds__(512, 4) void k_fc1_mfma(
        const short* __restrict__ A,      // spk2 bf16 bits [256][16384]
        const float* __restrict__ W,      // fc1 [4096][16384]
        float* __restrict__ part) {       // [8][256][4096]
    int b  = blockIdx.x;                  // 512 = 64nt * 8ks
    int nt = b & 63;
    int ks = b >> 6;
    int o0 = nt * 64;
    int kbase = ks * 2048;

    int tid  = threadIdx.x;
    int lane = tid & 63;
    int wv   = tid >> 6;                  // 0..7
    int mq   = wv >> 1;                   // M quarter (64 rows)
    int oh   = wv & 1;                    // output half (32 of 64)
    int lm   = lane & 15;
    int kq   = lane >> 4;

    __shared__ short Asm[2][8192];        // 2 x 16 KB A slab (swizzled)
    __shared__ short Wbf[2][6144];        // 2 x 12 KB pre-split W bf16
                                          //   [sp][row 64][chunk 4 x 8 shorts]

    // A DMA source (inverse swizzle on source; dest linear):
    // phys unit p = q*512+tid: r=p>>2, slot=(p&3)^((r>>1)&3)
    const short* gA[2];
#pragma unroll
    for (int q = 0; q < 2; q++) {
        int p = q * 512 + tid;
        int r = p >> 2;
        int c = (p & 3) ^ ((r >> 1) & 3);
        gA[q] = A + (size_t)r * 16384 + kbase + c * 8;
    }

    // W global load: thread covers row=tid>>3 (o0+row), k4=(tid&7)*4
    int wrow = tid >> 3;                  // 0..63
    const float* gWf = W + (size_t)(o0 + wrow) * 16384 + kbase + (tid & 7) * 4;

    // W bf16 write offset (shorts): row*32 + physchunk*8 + half*4 (+ sp*2048)
    {
    }
    int wkc   = (tid & 7) >> 1;
    int whalf = tid & 1;
    int wwoff = wrow * 32 + (wkc ^ ((wrow >> 1) & 3)) * 8 + whalf * 4;

    // LDS read offsets (swizzled)
    int aoff[4];                          // shorts
#pragma unroll
    for (int i = 0; i < 4; i++) {
        int r = mq * 64 + i * 16 + lm;
        aoff[i] = (r * 4 + (kq ^ ((r >> 1) & 3))) * 8;
    }
    int wroff[2];                         // shorts (+ sp*2048)
#pragma unroll
    for (int oi = 0; oi < 2; oi++) {
        int row = (2 * oh + oi) * 16 + lm;
        wroff[oi] = row * 32 + (kq ^ ((row >> 1) & 3)) * 8;
    }

    f32x4 acc[4][2];
#pragma unroll
    for (int i = 0; i < 4; i++)
#pragma unroll
        for (int oi = 0; oi < 2; oi++) acc[i][oi] = (f32x4){0.f, 0.f, 0.f, 0.f};

    // prologue: W(0) split -> Wbf[0]; W(1) into regs; A(0) DMA
    float4 wA = *(const float4*)gWf;          // W it=0
    load_lds16(gA[0], &Asm[0][wv * 512]);
    load_lds16(gA[1], &Asm[0][4096 + wv * 512]);
    {
        s16x4 h4, m4, l4;
        split3w4(wA, h4, m4, l4);
        *(s16x4*)&Wbf[0][wwoff]        = h4;
        *(s16x4*)&Wbf[0][2048 + wwoff] = m4;
        *(s16x4*)&Wbf[0][4096 + wwoff] = l4;
    }
    float4 wB = *(const float4*)(gWf + 32);   // W it=1
    __syncthreads();

    // body: wsplit holds W(it+1) fp32; wload will receive W(it+2)
    auto body = [&](int it, float4& wsplit, float4& wload) {
        int nb = (it + 1) & 1;
        if (it < 63) {
            load_lds16(gA[0] + (it + 1) * 32, &Asm[nb][wv * 512]);
            load_lds16(gA[1] + (it + 1) * 32, &Asm[nb][4096 + wv * 512]);
            s16x4 h4, m4, l4;
            split3w4(wsplit, h4, m4, l4);
            *(s16x4*)&Wbf[nb][wwoff]        = h4;
            *(s16x4*)&Wbf[nb][2048 + wwoff] = m4;
            *(s16x4*)&Wbf[nb][4096 + wwoff] = l4;
        }
        if (it < 62)
            wload = *(const float4*)(gWf + (it + 2) * 32);

        const short* as = Asm[it & 1];
        const short* wb = Wbf[it & 1];
        s16x8 av[4];
#pragma unroll
        for (int i = 0; i < 4; i++)
            av[i] = *(const s16x8*)(as + aoff[i]);
        s16x8 bfr[3][2];                  // [sp][oi]
#pragma unroll
        for (int oi = 0; oi < 2; oi++)
#pragma unroll
            for (int sp = 0; sp < 3; sp++)
                bfr[sp][oi] = *(const s16x8*)(wb + sp * 2048 + wroff[oi]);

#pragma unroll
        for (int i = 0; i < 4; i++)
#pragma unroll
            for (int oi = 0; oi < 2; oi++) {
                acc[i][oi] = __builtin_amdgcn_mfma_f32_16x16x32_bf16(
                    av[i], bfr[0][oi], acc[i][oi], 0, 0, 0);
                acc[i][oi] = __builtin_amdgcn_mfma_f32_16x16x32_bf16(
                    av[i], bfr[1][oi], acc[i][oi], 0, 0, 0);
                acc[i][oi] = __builtin_amdgcn_mfma_f32_16x16x32_bf16(
                    av[i], bfr[2][oi], acc[i][oi], 0, 0, 0);
            }

        __syncthreads();                  // drains DMA + ds_writes; swap
    };

#pragma unroll 1
    for (int j = 0; j < 32; ++j) {
        body(2 * j,     wB, wA);
        body(2 * j + 1, wA, wB);
    }

    int col = lane & 15;
    int rq  = (lane >> 4) * 4;
#pragma unroll
    for (int i = 0; i < 4; i++)
#pragma unroll
        for (int oi = 0; oi < 2; oi++)
#pragma unroll
            for (int r = 0; r < 4; r++) {
                int m = mq * 64 + i * 16 + rq + r;
                int o = o0 + (2 * oh + oi) * 16 + col;
                part[((size_t)ks * 256 + m) * 4096 + o] = acc[i][oi][r];
            }
}

// ----------------------------------------------- K-split reduce + IF for fc1
__global__ void k_fc1_if(const float* __restrict__ part,
                         float* __restrict__ spk3) {
    int idx = blockIdx.x * 256 + threadIdx.x;   // 131072
    int o = idx & 4095;
    int n = idx >> 12;
    float v = 0.f;
    for (int t = 0; t < T_STEPS; t++) {
        int m = t * NB + n;
        float s = 0.f;
#pragma unroll
        for (int ks = 0; ks < 8; ks++)
            s += part[((size_t)ks * 256 + m) * 4096 + o];
        v += s;
        float sp = (v >= 1.f) ? 1.f : 0.f;
        if (sp > 0.f) v = 0.f;
        spk3[(size_t)m * 4096 + o] = sp;
    }
}

// ------------------------------------------------------ fc2 + IF + time-mean
__global__ __launch_bounds__(256) void k_fc2_if_mean(
        const float* __restrict__ spk3, const float* __restrict__ fc2,
        float* __restrict__ out) {
    int b = blockIdx.x;                  // 320 = 32n * 10o
    int n = b / 10, o = b % 10;
    const float* wr = fc2 + o * 4096;
    __shared__ float red[256];
    int tid = threadIdx.x;
    float v = 0.f, cnt = 0.f;
    for (int t = 0; t < T_STEPS; t++) {
        const float* row = spk3 + (size_t)(t * NB + n) * 4096;
        float p = 0.f;
        for (int i = tid; i < 4096; i += 256) p += row[i] * wr[i];
        red[tid] = p;
        __syncthreads();
        for (int s = 128; s > 0; s >>= 1) {
            if (tid < s) red[tid] += red[tid + s];
            __syncthreads();
        }
        if (tid == 0) {
            v += red[0];
            float sp = (v >= 1.f) ? 1.f : 0.f;
            cnt += sp;
            if (sp > 0.f) v = 0.f;
        }
        __syncthreads();
    }
    if (tid == 0) out[n * 10 + o] = cnt * 0.125f;
}

// ---------------------------------------------------------------------- launch
extern "C" void kernel_launch(void* const* d_in, const int* in_sizes, int n_in,
                              void* d_out, int out_size, void* d_ws, size_t ws_size,
                              hipStream_t stream) {
    const float* x   = (const float*)d_in[0];   // [8,32,3,64,64]
    const float* w1  = (const float*)d_in[1];   // [64,3,3,3]
    const float* w2  = (const float*)d_in[2];   // [64,64,3,3]
    const float* fc1 = (const float*)d_in[3];   // [4096,16384]
    const float* fc2 = (const float*)d_in[4];   // [10,4096]
    float* out = (float*)d_out;                 // [32,10]

    float* ws = (float*)d_ws;
    // workspace layout (float slots)
    const size_t off_w2s   = 0;                          // 57344 (110592 bf16)
    const size_t off_spk1p = 57344;                      // 8388608 (16.8M bf16)
    const size_t off_spk2  = off_spk1p + 8388608;        // 2097152 (4.2M bf16)
    const size_t off_part  = off_spk2 + 2097152;         // 8388608
    const size_t off_spk3  = off_part + 8388608;         // 1048576
    __bf16* w2s   = (__bf16*)(ws + off_w2s);
    __bf16* spk1p = (__bf16*)(ws + off_spk1p);
    __bf16* spk2  = (__bf16*)(ws + off_spk2);
    float*  part  = ws + off_part;
    float*  spk3  = ws + off_spk3;

    k_w2s<<<144, 256, 0, stream>>>(w2, w2s);
    k_conv1_if_pool<<<1024, 256, 0, stream>>>(x, w1, spk1p);
    k_conv2_if_pool<<<256, 512, 0, stream>>>((const short*)spk1p,
                                             (const short*)w2s, spk2);
    k_fc1_mfma<<<512, 512, 0, stream>>>((const short*)spk2, fc1, part);
    k_fc1_if<<<512, 256, 0, stream>>>(part, spk3);
    k_fc2_if_mean<<<320, 256, 0, stream>>>(spk3, fc2, out);
}